// Round 15
// baseline (177.873 us; speedup 1.0000x reference)
//
#include <hip/hip_runtime.h>
#include <hip/hip_bf16.h>

// Problem: T=2048, B=32, H=512
//   scores[b,t] = sum_o v[o] * tanh( hb[b,o] + sum_h enc[t,b,h] * W2[o,h] )
//   out[b,0,t]  = softmax_t(scores[b,:])
//
// R15: persistent-B, barrier-free K-loop.
//  - Block owns a 64-col o-panel; full B panel (64 cols x 512 k, bf16) loaded
//    ONCE into LDS in MFMA-fragment-major order (conflict-free ds_read_b128).
//  - A streamed global->reg->cvt->MFMA. NO barriers in the K-loop; waves
//    independent (this kills the barrier-coupled staging that capped R8-R14).
//  - Each wave owns 256 rows; epilogue writes its rows directly (no reduce).
//  - Grid 512 = 8 panels x 64 M-blocks, XCD-remapped (nt-siblings co-XCD).

#define TT 2048
#define BB 32
#define HH 512

typedef __attribute__((ext_vector_type(8))) short bf16x8;
typedef __attribute__((ext_vector_type(4))) float f32x4;

static __device__ __forceinline__ unsigned cvt2(float a, float b) {
    union { __hip_bfloat162 h; unsigned u; } cv;
    cv.h = __float22bfloat162_rn(make_float2(a, b));   // v_cvt_pk_bf16_f32
    return cv.u;
}

static __device__ __forceinline__ unsigned short f2bf(float f) {
    unsigned int u = __float_as_uint(f);
    unsigned int r = (u + 0x7FFFu + ((u >> 16) & 1u)) >> 16;  // RNE
    return (unsigned short)r;
}

// tanh(x) = 1 - 2/(1+e^{2x});  inf-safe at both ends.
static __device__ __forceinline__ float fast_tanh(float x) {
    float e = __expf(2.0f * x);
    return 1.0f - 2.0f * __builtin_amdgcn_rcpf(1.0f + e);
}

static __device__ __forceinline__ void gload_lds16(const void* g, void* l) {
    __builtin_amdgcn_global_load_lds(
        (const __attribute__((address_space(1))) unsigned int*)g,
        (__attribute__((address_space(3))) unsigned int*)l, 16, 0, 0);
}

// ---- Kernel 1: pack W2 (= W_attn[:, 512:1024]) into fragment-major panels.
// Panel nt (64 cols): slot s = kblk*4 + cb (kblk 0..15, cb 0..3); lane 0..63;
// element e 0..7:  idx = nt*32768 + s*512 + lane*8 + e
//   holds W2[o = nt*64 + cb*16 + (lane&15)][k = kblk*32 + (lane>>4)*8 + e]
__global__ void pack_w2_kernel(const float* __restrict__ W, short* __restrict__ W2p) {
    int idx = blockIdx.x * 256 + threadIdx.x;      // 262144 total
    int e  = idx & 7;
    int ln = (idx >> 3) & 63;
    int fs = (idx >> 9) & 63;
    int nt = idx >> 15;
    int cb = fs & 3, kblk = fs >> 2;
    int o  = nt * 64 + cb * 16 + (ln & 15);
    int k  = kblk * 32 + (ln >> 4) * 8 + e;
    W2p[idx] = (short)f2bf(W[o * 1024 + 512 + k]);
}

// ---- Kernel 2: hb[b][o] = b_attn[o] + sum_h hidden[b,h] * W_attn[o,h]
__global__ void hb_kernel(const float* __restrict__ hidden, const float* __restrict__ W,
                          const float* __restrict__ b_attn, float* __restrict__ hb) {
    __shared__ float hrow[512];
    int b = blockIdx.x >> 1;
    int o = ((blockIdx.x & 1) << 8) + threadIdx.x;
    for (int h = threadIdx.x; h < 512; h += 256) hrow[h] = hidden[b * 512 + h];
    __syncthreads();
    const float4* wr = reinterpret_cast<const float4*>(W + (size_t)o * 1024);
    const float4* hr = reinterpret_cast<const float4*>(hrow);
    float acc = b_attn[o];
#pragma unroll 8
    for (int i = 0; i < 128; ++i) {
        float4 w = wr[i], h4 = hr[i];
        acc += w.x * h4.x + w.y * h4.y + w.z * h4.z + w.w * h4.w;
    }
    hb[b * 512 + o] = acc;
}

// ---- Kernel 3: persistent-B barrier-free GEMM + fused tanh/v-dot.
// Grid 512, 256 threads (4 waves). bid -> xcd=bid&7, loc=bid>>3;
// nt = loc&7 (64-col panel), mblk = xcd*8 + (loc>>3) (1024 rows).
// Wave w owns rows mblk*1024 + w*256 .. +256, in 4 groups of 64.
// Per group: acc[4][4] over full K (16 kblks of 32), A direct from global.
__global__ void attn_main_kernel(
    const float* __restrict__ enc, const short* __restrict__ W2p,
    const float* __restrict__ hb, const float* __restrict__ v,
    float* __restrict__ scores_part)
{
    __shared__ short Bp[32768];          // 64KB fragment-major B panel

    const int tid = threadIdx.x;
    const int bid = blockIdx.x;
    const int loc = bid >> 3;
    const int nt = loc & 7;
    const int mblk = (bid & 7) * 8 + (loc >> 3);

    const int wave = tid >> 6;
    const int lane = tid & 63;
    const int lcol = lane & 15;
    const int lq = lane >> 4;

    // ---- stage B panel once: 64KB, per-wave 16KB, 16 chunks of 1KB
    {
        const short* src = W2p + (size_t)nt * 32768 + wave * 8192 + lane * 8;
#pragma unroll
        for (int i = 0; i < 16; ++i)
            gload_lds16(src + i * 512, &Bp[wave * 8192 + i * 512]);
    }
    __syncthreads();   // the ONLY block-wide barrier

    const int rowbase = mblk * 1024 + wave * 256;
    const float* vbase = v + nt * 64;
    // per-lane A source: row rowbase+g*64+rf*16+lcol, k = kblk*32 + lq*8
    const float* abase = enc + (size_t)(rowbase + lcol) * HH + lq * 8;

#pragma unroll 1
    for (int g = 0; g < 4; ++g) {
        f32x4 acc[4][4];
#pragma unroll
        for (int i = 0; i < 4; ++i)
#pragma unroll
            for (int j = 0; j < 4; ++j) acc[i][j] = (f32x4){0.f, 0.f, 0.f, 0.f};

        const float* ag = abase + (size_t)g * 64 * HH;

#pragma unroll 4
        for (int kblk = 0; kblk < 16; ++kblk) {
            // A fragments: 4 row-frags x (16 rows, 32 k); lane: 8 fp32 = 2 float4
            bf16x8 af[4];
#pragma unroll
            for (int rf = 0; rf < 4; ++rf) {
                const float* s = ag + (size_t)rf * 16 * HH + kblk * 32;
                const float4 lo = *reinterpret_cast<const float4*>(s);
                const float4 hi = *reinterpret_cast<const float4*>(s + 4);
                union { bf16x8 v8; uint4 u; } pk;
                pk.u.x = cvt2(lo.x, lo.y);
                pk.u.y = cvt2(lo.z, lo.w);
                pk.u.z = cvt2(hi.x, hi.y);
                pk.u.w = cvt2(hi.z, hi.w);
                af[rf] = pk.v8;
            }
            // B fragments: 4 col-frags from LDS (fragment-major, conflict-free)
            bf16x8 bf[4];
#pragma unroll
            for (int cb = 0; cb < 4; ++cb)
                bf[cb] = *reinterpret_cast<const bf16x8*>(
                    &Bp[(kblk * 4 + cb) * 512 + lane * 8]);
#pragma unroll
            for (int rf = 0; rf < 4; ++rf)
#pragma unroll
                for (int cb = 0; cb < 4; ++cb)
                    acc[rf][cb] = __builtin_amdgcn_mfma_f32_16x16x32_bf16(
                        af[rf], bf[cb], acc[rf][cb], 0, 0, 0);
        }

        // ---- epilogue for this 64-row group: tanh + v-dot + column reduce
        float part[4][4];
#pragma unroll
        for (int rf = 0; rf < 4; ++rf)
#pragma unroll
            for (int j = 0; j < 4; ++j) part[rf][j] = 0.0f;

#pragma unroll
        for (int cb = 0; cb < 4; ++cb) {
            const int o = nt * 64 + cb * 16 + lcol;
            const float hbv = hb[((rowbase) & 31) * 512 + o];  // placeholder, fixed below
            (void)hbv;
        }
        // NOTE: hb depends on b = row & 31, which varies per acc ROW, while
        // lane&15 indexes the COLUMN. acc[rf][cb][j] is row rf*16+lq*4+j,
        // col cb*16+lcol. b = (rowbase + g*64 + rf*16 + lq*4 + j) & 31.
#pragma unroll
        for (int cb = 0; cb < 4; ++cb) {
            const int o = nt * 64 + cb * 16 + lcol;
            const float vv = vbase[cb * 16 + lcol];
            const float* hbcol = hb + o;
#pragma unroll
            for (int rf = 0; rf < 4; ++rf)
#pragma unroll
                for (int j = 0; j < 4; ++j) {
                    const int b = (rowbase + g * 64 + rf * 16 + lq * 4 + j) & 31;
                    const float x = acc[rf][cb][j] + hbcol[b * 512];
                    part[rf][j] = fmaf(fast_tanh(x), vv, part[rf][j]);
                }
        }

#pragma unroll
        for (int off = 1; off < 16; off <<= 1)
#pragma unroll
            for (int rf = 0; rf < 4; ++rf)
#pragma unroll
                for (int j = 0; j < 4; ++j)
                    part[rf][j] += __shfl_xor(part[rf][j], off, 64);

        if (lcol == 0) {
#pragma unroll
            for (int rf = 0; rf < 4; ++rf)
#pragma unroll
                for (int j = 0; j < 4; ++j) {
                    const int R = rowbase + g * 64 + rf * 16 + lq * 4 + j;
                    const int b = R & 31, t = R >> 5;
                    scores_part[((size_t)nt * BB + b) * TT + t] = part[rf][j];
                }
        }
    }
}

// ---- Kernel 4: sum 8 panel partials + softmax over T per b
__global__ void softmax_kernel(const float* __restrict__ sp, float* __restrict__ out) {
    __shared__ float wred[4];
    __shared__ float wsum[4];
    const int b = blockIdx.x;
    const int tid = threadIdx.x;   // 256
    float vals[8];
    float mx = -1e30f;
#pragma unroll
    for (int i = 0; i < 8; ++i) {
        const int t = i * 256 + tid;
        float s = 0.0f;
#pragma unroll
        for (int p = 0; p < 8; ++p)
            s += sp[((size_t)p * BB + b) * TT + t];
        vals[i] = s;
        mx = fmaxf(mx, s);
    }
#pragma unroll
    for (int off = 32; off; off >>= 1) mx = fmaxf(mx, __shfl_xor(mx, off, 64));
    if ((tid & 63) == 0) wred[tid >> 6] = mx;
    __syncthreads();
    mx = fmaxf(fmaxf(wred[0], wred[1]), fmaxf(wred[2], wred[3]));
    float s = 0.0f;
#pragma unroll
    for (int i = 0; i < 8; ++i) {
        vals[i] = __expf(vals[i] - mx);
        s += vals[i];
    }
#pragma unroll
    for (int off = 32; off; off >>= 1) s += __shfl_xor(s, off, 64);
    if ((tid & 63) == 0) wsum[tid >> 6] = s;
    __syncthreads();
    s = wsum[0] + wsum[1] + wsum[2] + wsum[3];
    const float inv = 1.0f / s;
#pragma unroll
    for (int i = 0; i < 8; ++i) out[b * TT + i * 256 + tid] = vals[i] * inv;
}

extern "C" void kernel_launch(void* const* d_in, const int* in_sizes, int n_in,
                              void* d_out, int out_size, void* d_ws, size_t ws_size,
                              hipStream_t stream) {
    const float* hidden = (const float*)d_in[0];   // (1,B,H)
    const float* enc    = (const float*)d_in[1];   // (T,B,H)
    const float* W      = (const float*)d_in[2];   // (H,2H)
    const float* b_attn = (const float*)d_in[3];   // (H,)
    const float* v      = (const float*)d_in[4];   // (H,)
    float* out = (float*)d_out;                    // (B,1,T)

    char* base = (char*)d_ws;
    short* W2p = (short*)base;                          // 512*512*2 = 524288 B
    float* hb  = (float*)(base + 524288);               // 32*512*4  =  65536 B
    float* sp  = (float*)(base + 589824);               // 8*32*2048*4 = 2097152 B

    pack_w2_kernel<<<1024, 256, 0, stream>>>(W, W2p);
    hb_kernel<<<64, 256, 0, stream>>>(hidden, W, b_attn, hb);
    attn_main_kernel<<<512, 256, 0, stream>>>(enc, W2p, hb, v, sp);
    softmax_kernel<<<32, 256, 0, stream>>>(sp, out);
}

// Round 16
// 79.907 us; speedup vs baseline: 2.2260x; 2.2260x over previous
//
#include <hip/hip_runtime.h>
#include <hip/hip_bf16.h>

// Problem: T=2048, B=32, H=512
//   scores[b,t] = sum_o v[o] * tanh( hb[b,o] + sum_h enc[t,b,h] * W2[o,h] )
//   out[b,0,t]  = softmax_t(scores[b,:])
//
// FINAL STRUCTURE (= R10, best verified 83.5us, + merged prep launch):
//  - R8/R9/R10 main: 128x128 tile, dbuf LDS, B via global_load_lds from
//    pre-swizzled image (per-wave dests), A reg-staged dist-2 ping-pong,
//    XCD remap. 0 bank conflicts, 0 spill, FETCH ~71MB.
//  - Hard-won: WRITE>>2MB = spill (rotating reg arrays / min-waves>=4 /
//    unbounded high-occupancy targets all trigger it); occupancy x2 null
//    (R6,R13); counted vmcnt / raw barrier / setprio negative (R11);
//    8-phase 256^2 worse at this shape (R14); barrier-free persistent-B
//    fails on spill + uncoalesced A gather (R15).
//  - This round: pack_w2 + hb merged into ONE prep kernel (concurrent).

#define TT 2048
#define BB 32
#define HH 512

typedef __attribute__((ext_vector_type(8))) short bf16x8;
typedef __attribute__((ext_vector_type(4))) float f32x4;

static __device__ __forceinline__ unsigned cvt2(float a, float b) {
    union { __hip_bfloat162 h; unsigned u; } cv;
    cv.h = __float22bfloat162_rn(make_float2(a, b));   // v_cvt_pk_bf16_f32
    return cv.u;
}

static __device__ __forceinline__ unsigned short f2bf(float f) {
    unsigned int u = __float_as_uint(f);
    unsigned int r = (u + 0x7FFFu + ((u >> 16) & 1u)) >> 16;  // RNE
    return (unsigned short)r;
}

// tanh(x) = 1 - 2/(1+e^{2x});  inf-safe at both ends.
static __device__ __forceinline__ float fast_tanh(float x) {
    float e = __expf(2.0f * x);
    return 1.0f - 2.0f * __builtin_amdgcn_rcpf(1.0f + e);
}

static __device__ __forceinline__ void gload_lds16(const void* g, void* l) {
    __builtin_amdgcn_global_load_lds(
        (const __attribute__((address_space(1))) unsigned int*)g,
        (__attribute__((address_space(3))) unsigned int*)l, 16, 0, 0);
}

// ---- Kernel 1 (merged prep): blocks [0,1024) pack W2 into the swizzled LDS
// image; blocks [1024,1088) compute hb. Independent jobs, one launch.
// W2p layout: idx = nt*65536 + ks*8192 + j*64 + c (shorts);
//   element = W2[nt*128+j][ks*64 + (c ^ ((j&7)<<3))]
__global__ void prep_kernel(const float* __restrict__ W,
                            const float* __restrict__ hidden,
                            const float* __restrict__ b_attn,
                            short* __restrict__ W2p,
                            float* __restrict__ hb) {
    __shared__ float hrow[512];
    const int bid = blockIdx.x;
    if (bid < 1024) {
        int idx = bid * 256 + threadIdx.x;      // 262144 total
        int nt = idx >> 16;
        int ks = (idx >> 13) & 7;
        int s  = idx & 8191;
        int j  = s >> 6;
        int c  = s & 63;
        int kk = c ^ ((j & 7) << 3);
        int o  = nt * 128 + j;
        int k  = ks * 64 + kk;
        W2p[idx] = (short)f2bf(W[o * 1024 + 512 + k]);
    } else {
        const int hbid = bid - 1024;
        int b = hbid >> 1;
        int o = ((hbid & 1) << 8) + threadIdx.x;
        for (int h = threadIdx.x; h < 512; h += 256) hrow[h] = hidden[b * 512 + h];
        __syncthreads();
        const float4* wr = reinterpret_cast<const float4*>(W + (size_t)o * 1024);
        const float4* hr = reinterpret_cast<const float4*>(hrow);
        float acc = b_attn[o];
#pragma unroll 8
        for (int i = 0; i < 128; ++i) {
            float4 w = wr[i], h4 = hr[i];
            acc += w.x * h4.x + w.y * h4.y + w.z * h4.z + w.w * h4.w;
        }
        hb[b * 512 + o] = acc;
    }
}

// ---- Kernel 2: 128x128-tile double-buffered GEMM + fused tanh/v-dot epilogue.
// Grid: 2048 blocks, XCD remap w=(bid&7)*256+(bid>>3); nt=w&3, mtile=w>>2.
// 256 threads = 4 waves (wr x wc = 2x2), each wave computes 64x64.
// K = 512 in 8 steps of 64. A: dist-2 reg prefetch (rA0/rA1) -> cvt -> ds_write.
// B: global_load_lds from pre-swizzled W2p, 1-ahead, per-wave dests.
__global__ __launch_bounds__(256, 2) void attn_main_kernel(
    const float* __restrict__ enc, const short* __restrict__ W2p,
    const float* __restrict__ hb, const float* __restrict__ v,
    float* __restrict__ scores_part)
{
    __shared__ short As[2][128 * 64];   // 16KB x2, swizzled: col c2 = c ^ ((r&7)<<3)
    __shared__ short Bs[2][128 * 64];   // 16KB x2, image pre-swizzled by prep kernel
    __shared__ float s_red[2][128];

    const int tid = threadIdx.x;
    const int bid = blockIdx.x;
    const int w = (bid & 7) * 256 + (bid >> 3);  // XCD-contiguous work id (bijective)
    const int nt = w & 3;                // N-tile (128 o-cols)
    const int mtile = w >> 2;            // 512 M-tiles
    const int b = mtile >> 4;            // batch
    const int t0 = (mtile & 15) * 128;   // t-range base

    const int wave = tid >> 6;
    const int lane = tid & 63;
    const int wr = wave >> 1;            // row half (64 rows)
    const int wc = wave & 1;             // col half (64 cols)
    const int lcol = lane & 15;
    const int lq = lane >> 4;

    // A staging geometry: pass p: row r = p*32 + (tid>>3), float col (tid&7)*8
    const int arow = tid >> 3;           // 0..31
    const int afc = (tid & 7) * 8;       // 0..56
    const float* encbase = enc + ((size_t)(t0 + arow) * BB + b) * HH + afc;
    // B staging source (shorts): + ks*8192 per step; lane offset baked in
    const short* bsrc = W2p + nt * 65536 + (wave * 4) * 512 + lane * 8;

    f32x4 acc[4][4];
#pragma unroll
    for (int mt = 0; mt < 4; ++mt)
#pragma unroll
        for (int ns = 0; ns < 4; ++ns) acc[mt][ns] = (f32x4){0.f, 0.f, 0.f, 0.f};

    float4 rA0[8], rA1[8];

#define A_LOAD(RA, KS)                                                              \
    {                                                                               \
        _Pragma("unroll")                                                           \
        for (int p = 0; p < 4; ++p) {                                               \
            const float* src = encbase + (size_t)p * 32 * BB * HH + (KS) * 64;      \
            RA[p * 2]     = *reinterpret_cast<const float4*>(src);                  \
            RA[p * 2 + 1] = *reinterpret_cast<const float4*>(src + 4);              \
        }                                                                           \
    }

#define B_STAGE(KS, BUF)                                                            \
    {                                                                               \
        const short* s0 = bsrc + (KS) * 8192;                                       \
        _Pragma("unroll")                                                           \
        for (int c = 0; c < 4; ++c)                                                 \
            gload_lds16(s0 + c * 512, &Bs[BUF][(wave * 4 + c) * 512]);              \
    }

#define A_WRITE(RA, BUF)                                                            \
    {                                                                               \
        _Pragma("unroll")                                                           \
        for (int p = 0; p < 4; ++p) {                                               \
            const int r = p * 32 + arow;                                            \
            uint4 pk;                                                               \
            pk.x = cvt2(RA[p * 2].x, RA[p * 2].y);                                  \
            pk.y = cvt2(RA[p * 2].z, RA[p * 2].w);                                  \
            pk.z = cvt2(RA[p * 2 + 1].x, RA[p * 2 + 1].y);                          \
            pk.w = cvt2(RA[p * 2 + 1].z, RA[p * 2 + 1].w);                          \
            const int cs = afc ^ ((r & 7) << 3);                                    \
            *reinterpret_cast<uint4*>(&As[BUF][r * 64 + cs]) = pk;                  \
        }                                                                           \
    }

#define COMPUTE(BUF)                                                                \
    {                                                                               \
        _Pragma("unroll")                                                           \
        for (int ksub = 0; ksub < 2; ++ksub) {                                      \
            const int kk = ksub * 32 + lq * 8;                                      \
            bf16x8 af[4], bfr[4];                                                   \
            _Pragma("unroll")                                                       \
            for (int mt = 0; mt < 4; ++mt) {                                        \
                const int r = wr * 64 + mt * 16 + lcol;                             \
                af[mt] = *reinterpret_cast<const bf16x8*>(                          \
                    &As[BUF][r * 64 + (kk ^ ((r & 7) << 3))]);                      \
            }                                                                       \
            _Pragma("unroll")                                                       \
            for (int ns = 0; ns < 4; ++ns) {                                        \
                const int j = wc * 64 + ns * 16 + lcol;                             \
                bfr[ns] = *reinterpret_cast<const bf16x8*>(                         \
                    &Bs[BUF][j * 64 + (kk ^ ((j & 7) << 3))]);                      \
            }                                                                       \
            _Pragma("unroll")                                                       \
            for (int mt = 0; mt < 4; ++mt)                                          \
                _Pragma("unroll")                                                   \
                for (int ns = 0; ns < 4; ++ns)                                      \
                    acc[mt][ns] = __builtin_amdgcn_mfma_f32_16x16x32_bf16(          \
                        af[mt], bfr[ns], acc[mt][ns], 0, 0, 0);                     \
        }                                                                           \
    }

    // ---- prologue: stage step 0; preload step 1 into rA1
    A_LOAD(rA0, 0);
    A_LOAD(rA1, 1);
    B_STAGE(0, 0);
    A_WRITE(rA0, 0);     // vmcnt stall here only (prologue)
    __syncthreads();     // drains gload_lds for step 0

    // ---- main K-loop: 8 steps, hand-unrolled x2, static ping-pong.
    // Data for step s: loaded at s-2 (rA_{s&1}), LDS-written at s-1, computed at s.
#pragma unroll
    for (int s2 = 0; s2 < 4; ++s2) {
        const int s = s2 * 2;
        // ---- even step s: compute buf0
        if (s + 2 < 8) A_LOAD(rA0, s + 2);
        B_STAGE(s + 1, 1);
        COMPUTE(0);
        A_WRITE(rA1, 1);                    // data for step s+1 (loaded at s-1)
        __syncthreads();
        // ---- odd step s+1: compute buf1
        if (s + 3 < 8) A_LOAD(rA1, s + 3);
        if (s + 2 < 8) B_STAGE(s + 2, 0);
        COMPUTE(1);
        if (s + 2 < 8) {
            A_WRITE(rA0, 0);                // data for step s+2 (loaded at s)
            __syncthreads();
        }
    }

    // ---- epilogue: tanh + v-dot, reduce over this block's 128 cols
    float part[4][4];
#pragma unroll
    for (int mt = 0; mt < 4; ++mt)
#pragma unroll
        for (int j = 0; j < 4; ++j) part[mt][j] = 0.0f;

#pragma unroll
    for (int ns = 0; ns < 4; ++ns) {
        const int o = nt * 128 + wc * 64 + ns * 16 + lcol;
        const float hbv = hb[b * 512 + o];
        const float vv = v[o];
#pragma unroll
        for (int mt = 0; mt < 4; ++mt)
#pragma unroll
            for (int j = 0; j < 4; ++j)
                part[mt][j] = fmaf(fast_tanh(acc[mt][ns][j] + hbv), vv, part[mt][j]);
    }

#pragma unroll
    for (int off = 1; off < 16; off <<= 1)
#pragma unroll
        for (int mt = 0; mt < 4; ++mt)
#pragma unroll
            for (int j = 0; j < 4; ++j)
                part[mt][j] += __shfl_xor(part[mt][j], off, 64);

    if (lcol == 0) {
#pragma unroll
        for (int mt = 0; mt < 4; ++mt)
#pragma unroll
            for (int j = 0; j < 4; ++j)
                s_red[wc][wr * 64 + mt * 16 + lq * 4 + j] = part[mt][j];
    }
    __syncthreads();

    if (tid < 128)
        scores_part[((size_t)nt * BB + b) * TT + t0 + tid] =
            s_red[0][tid] + s_red[1][tid];
}

// ---- Kernel 3: sum 4 N-tile partials + softmax over T per b
__global__ void softmax_kernel(const float* __restrict__ sp, float* __restrict__ out) {
    __shared__ float wred[4];
    __shared__ float wsum[4];
    const int b = blockIdx.x;
    const int tid = threadIdx.x;   // 256
    float vals[8];
    float mx = -1e30f;
#pragma unroll
    for (int i = 0; i < 8; ++i) {
        const int t = i * 256 + tid;
        const float s = sp[(size_t)b * TT + t] + sp[((size_t)BB + b) * TT + t] +
                        sp[((size_t)2 * BB + b) * TT + t] + sp[((size_t)3 * BB + b) * TT + t];
        vals[i] = s;
        mx = fmaxf(mx, s);
    }
#pragma unroll
    for (int off = 32; off; off >>= 1) mx = fmaxf(mx, __shfl_xor(mx, off, 64));
    if ((tid & 63) == 0) wred[tid >> 6] = mx;
    __syncthreads();
    mx = fmaxf(fmaxf(wred[0], wred[1]), fmaxf(wred[2], wred[3]));
    float s = 0.0f;
#pragma unroll
    for (int i = 0; i < 8; ++i) {
        vals[i] = __expf(vals[i] - mx);
        s += vals[i];
    }
#pragma unroll
    for (int off = 32; off; off >>= 1) s += __shfl_xor(s, off, 64);
    if ((tid & 63) == 0) wsum[tid >> 6] = s;
    __syncthreads();
    s = wsum[0] + wsum[1] + wsum[2] + wsum[3];
    const float inv = 1.0f / s;
#pragma unroll
    for (int i = 0; i < 8; ++i) out[b * TT + i * 256 + tid] = vals[i] * inv;
}

extern "C" void kernel_launch(void* const* d_in, const int* in_sizes, int n_in,
                              void* d_out, int out_size, void* d_ws, size_t ws_size,
                              hipStream_t stream) {
    const float* hidden = (const float*)d_in[0];   // (1,B,H)
    const float* enc    = (const float*)d_in[1];   // (T,B,H)
    const float* W      = (const float*)d_in[2];   // (H,2H)
    const float* b_attn = (const float*)d_in[3];   // (H,)
    const float* v      = (const float*)d_in[4];   // (H,)
    float* out = (float*)d_out;                    // (B,1,T)

    char* base = (char*)d_ws;
    short* W2p = (short*)base;                          // 512*512*2 = 524288 B
    float* hb  = (float*)(base + 524288);               // 32*512*4  =  65536 B
    float* sp  = (float*)(base + 589824);               // 4*32*2048*4 = 1048576 B

    prep_kernel<<<1088, 256, 0, stream>>>(W, hidden, b_attn, W2p, hb);
    attn_main_kernel<<<2048, 256, 0, stream>>>(enc, W2p, hb, v, sp);
    softmax_kernel<<<32, 256, 0, stream>>>(sp, out);
}